// Round 4
// baseline (215.828 us; speedup 1.0000x reference)
//
#include <hip/hip_runtime.h>
#include <stdint.h>

// Problem constants
#define BB 8
#define DD 256
#define NN 2048
#define HH 4
#define HD 64
// 0.125 (1/sqrt(64)) * log2(e): puts scores in log2-domain so P = exp2(S)
#define SCALE_Q 0.18033688011112042f

typedef __attribute__((ext_vector_type(8))) short bf16x8;   // 8 bf16 = 4 VGPRs
typedef __attribute__((ext_vector_type(4))) float f32x4;
typedef __attribute__((ext_vector_type(16))) float f32x16;

// ---- helpers --------------------------------------------------------------

__device__ __forceinline__ void gld16(const void* g, void* l) {
  // async global->LDS, 16B per lane; LDS dest = wave-uniform base + lane*16
  __builtin_amdgcn_global_load_lds(
      (__attribute__((address_space(1))) void*)(void*)(uintptr_t)(g),
      (__attribute__((address_space(3))) void*)(l), 16, 0, 0);
}

__device__ __forceinline__ unsigned short f2bf(float f) {
  union { float f; unsigned u; } v; v.f = f;
  unsigned lsb = (v.u >> 16) & 1u;
  v.u += 0x7fffu + lsb;               // RNE
  return (unsigned short)(v.u >> 16);
}

// ---- X transpose+cast: fp32 [B][D][N] -> bf16 [B][N][D], 64x64 tiles ------

__global__ __launch_bounds__(256) void tcast_x(
    const float* __restrict__ q, const float* __restrict__ k,
    const float* __restrict__ v, unsigned short* __restrict__ oq,
    unsigned short* __restrict__ ok2, unsigned short* __restrict__ ov) {
  __shared__ float t[64][65];
  int z = blockIdx.z, src = z >> 3, b = z & 7;
  const float* ip = (src == 0 ? q : src == 1 ? k : v) + (long)b * DD * NN;
  unsigned short* op = (src == 0 ? oq : src == 1 ? ok2 : ov) + (long)b * NN * DD;
  int c0 = blockIdx.x * 64, r0 = blockIdx.y * 64;
  int tx = threadIdx.x & 63, ty = threadIdx.x >> 6;
#pragma unroll
  for (int rr = 0; rr < 16; rr++) {
    int r = rr * 4 + ty;
    t[r][tx] = ip[(long)(r0 + r) * NN + c0 + tx];
  }
  __syncthreads();
#pragma unroll
  for (int rr = 0; rr < 16; rr++) {
    int c = rr * 4 + ty;
    op[(long)(c0 + c) * DD + r0 + tx] = f2bf(t[tx][c]);
  }
}

// ---- W transpose+cast with head permutation -------------------------------
// z<3 (Wq/Wk/Wv): out[j'][d] = s*W[d][o], j' = h*64+hd where o = hd*4+h
// z=3 (Wm):       out[o2][k'] = W[p(k')][o2]  (k-dim permuted to match XA)

__global__ __launch_bounds__(256) void tcast_w(
    const float* __restrict__ Wq, const float* __restrict__ Wk,
    const float* __restrict__ Wv, const float* __restrict__ Wm,
    unsigned short* __restrict__ oWq, unsigned short* __restrict__ oWk,
    unsigned short* __restrict__ oWv, unsigned short* __restrict__ oWm) {
  __shared__ float t[32][33];
  int z = blockIdx.z;
  const float* ip = z == 0 ? Wq : z == 1 ? Wk : z == 2 ? Wv : Wm;
  unsigned short* op = z == 0 ? oWq : z == 1 ? oWk : z == 2 ? oWv : oWm;
  float s = z == 0 ? SCALE_Q : 1.f;
  int c0 = blockIdx.x * 32, r0 = blockIdx.y * 32;
  int tx = threadIdx.x & 31, ty = threadIdx.x >> 5;
#pragma unroll
  for (int rr = 0; rr < 4; rr++) {
    int r = rr * 8 + ty;
    t[r][tx] = ip[(long)(r0 + r) * DD + c0 + tx];
  }
  __syncthreads();
  if (z < 3) {
#pragma unroll
    for (int rr = 0; rr < 4; rr++) {
      int c = rr * 8 + ty;
      int o = c0 + c;
      int jp = ((o & 3) << 6) | (o >> 2);   // inv_p: o=hd*4+h -> j'=h*64+hd
      op[(long)jp * DD + r0 + tx] = f2bf(s * t[tx][c]);
    }
  } else {
#pragma unroll
    for (int rr = 0; rr < 4; rr++) {
      int c = rr * 8 + ty;
      int d = r0 + tx;
      int kp = ((d & 3) << 6) | (d >> 2);
      op[(long)(c0 + c) * DD + kp] = f2bf(t[tx][c]);
    }
  }
}

// ---- shared GEMM core: 128(i) x 64(j) tile, K=256, 2-phase pipelined ------
// C[i][j] = sum_k A[i][k]*B[j][k]; A,B row-major [*][256] bf16.
// 4 waves as 2x2, each wave 64x32. acc[4][2] of 16x16 frags.

#define GEMM_STAGE(kt, buf)                                                    \
  {                                                                            \
    int _kt = (kt);                                                            \
    _Pragma("unroll") for (int c = 0; c < 4; c++) {                            \
      int row = w * 32 + c * 8 + (lane >> 3);                                  \
      int so = ((lane & 7) * 16) ^ ((row & 7) << 4);                           \
      gld16((const char*)Ag + ((long)(i0 + row) * DD + _kt * 64) * 2 + so,     \
            (char*)&At[buf][0] + (w * 32 + c * 8) * 128);                      \
    }                                                                          \
    _Pragma("unroll") for (int c = 0; c < 2; c++) {                            \
      int row = w * 16 + c * 8 + (lane >> 3);                                  \
      int so = ((lane & 7) * 16) ^ ((row & 7) << 4);                           \
      gld16((const char*)Bg + ((long)(j0 + row) * DD + _kt * 64) * 2 + so,     \
            (char*)&Bt[buf][0] + (w * 16 + c * 8) * 128);                      \
    }                                                                          \
  }

#define GEMM_COMPUTE(buf)                                                      \
  _Pragma("unroll") for (int ks = 0; ks < 2; ks++) {                           \
    bf16x8 af[4], bfv[2];                                                      \
    _Pragma("unroll") for (int mi = 0; mi < 4; mi++) {                         \
      int row = wr * 64 + mi * 16 + (lane & 15);                               \
      int off = (ks * 64 + (lane >> 4) * 16) ^ ((row & 7) << 4);               \
      af[mi] = *(const bf16x8*)((const char*)&At[buf][0] + row * 128 + off);   \
    }                                                                          \
    _Pragma("unroll") for (int nj = 0; nj < 2; nj++) {                         \
      int row = wc * 32 + nj * 16 + (lane & 15);                               \
      int off = (ks * 64 + (lane >> 4) * 16) ^ ((row & 7) << 4);               \
      bfv[nj] = *(const bf16x8*)((const char*)&Bt[buf][0] + row * 128 + off);  \
    }                                                                          \
    _Pragma("unroll") for (int mi = 0; mi < 4; mi++)                           \
        _Pragma("unroll") for (int nj = 0; nj < 2; nj++)                       \
            acc[mi][nj] = __builtin_amdgcn_mfma_f32_16x16x32_bf16(             \
                af[mi], bfv[nj], acc[mi][nj], 0, 0, 0);                        \
  }

#define GEMM_MAIN()                                                            \
  f32x4 acc[4][2];                                                             \
  _Pragma("unroll") for (int a = 0; a < 4; a++)                                \
      _Pragma("unroll") for (int c = 0; c < 2; c++)                            \
          acc[a][c] = (f32x4){0.f, 0.f, 0.f, 0.f};                             \
  GEMM_STAGE(0, 0);                                                            \
  __syncthreads();                                                             \
  int buf = 0;                                                                 \
  for (int kt = 0; kt < 4; kt++) {                                             \
    if (kt < 3) GEMM_STAGE(kt + 1, buf ^ 1);                                   \
    GEMM_COMPUTE(buf);                                                         \
    __syncthreads();                                                           \
    buf ^= 1;                                                                  \
  }

// ---- fused QKV projection GEMM --------------------------------------------
// proj 0/1: C[n][j'=h*64+hd] -> Qh/Kh [b][h][n][hd]
// proj 2:   C[i'=h*64+hd][m] -> Vh [b][h][hd][m]

__global__ __launch_bounds__(256) void gemm_qkv(
    const unsigned short* __restrict__ Xq, const unsigned short* __restrict__ Xk,
    const unsigned short* __restrict__ Xv, const unsigned short* __restrict__ Wq,
    const unsigned short* __restrict__ Wk, const unsigned short* __restrict__ Wv,
    const float* __restrict__ bq, const float* __restrict__ bk,
    const float* __restrict__ bv, unsigned short* __restrict__ Qh,
    unsigned short* __restrict__ Kh, unsigned short* __restrict__ Vh) {
  __shared__ unsigned short At[2][128 * 64], Bt[2][64 * 64];
  int z = blockIdx.z, proj = z >> 3, bb = z & 7;
  int flat = blockIdx.y * 16 + blockIdx.x;  // 0..63
  const unsigned short *Ag, *Bg;
  const float* bias;
  float bsc = 1.f;
  int i0, j0;
  if (proj == 0) {
    Ag = Xq + (long)bb * NN * DD; Bg = Wq; bias = bq; bsc = SCALE_Q;
    i0 = (flat & 15) * 128; j0 = (flat >> 4) * 64;
  } else if (proj == 1) {
    Ag = Xk + (long)bb * NN * DD; Bg = Wk; bias = bk;
    i0 = (flat & 15) * 128; j0 = (flat >> 4) * 64;
  } else {
    Ag = Wv; Bg = Xv + (long)bb * NN * DD; bias = bv;
    i0 = (flat >> 5) * 128; j0 = (flat & 31) * 64;
  }
  int tid = threadIdx.x, lane = tid & 63, w = tid >> 6;
  int wr = w >> 1, wc = w & 1;

  GEMM_MAIN();

#pragma unroll
  for (int mi = 0; mi < 4; mi++) {
#pragma unroll
    for (int nj = 0; nj < 2; nj++) {
#pragma unroll
      for (int r = 0; r < 4; r++) {
        int ig = i0 + wr * 64 + mi * 16 + (lane >> 4) * 4 + r;
        int jg = j0 + wc * 32 + nj * 16 + (lane & 15);
        float v = acc[mi][nj][r];
        if (proj < 2) {
          int o = ((jg & 63) << 2) | (jg >> 6);
          v += bias[o] * bsc;
          int hh = jg >> 6, hd = jg & 63;
          unsigned short* dst = proj == 0 ? Qh : Kh;
          dst[(((long)bb * HH + hh) * NN + ig) * HD + hd] = f2bf(v);
        } else {
          int o = ((ig & 63) << 2) | (ig >> 6);
          v += bias[o];
          int hh = ig >> 6, hd = ig & 63;
          Vh[(((long)bb * HH + hh) * HD + hd) * NN + jg] = f2bf(v);
        }
      }
    }
  }
}

// ---- output projection: C[o2][n] = sum_k Wmt[o2][k]*XA[n][k] + bm ---------

__global__ __launch_bounds__(256) void gemm_out(
    const unsigned short* __restrict__ A, const unsigned short* __restrict__ B,
    const float* __restrict__ bias, float* __restrict__ out) {
  __shared__ unsigned short At[2][128 * 64], Bt[2][64 * 64];
  int bb = blockIdx.z;
  int flat = blockIdx.y * 16 + blockIdx.x;
  const unsigned short* Ag = A;
  const unsigned short* Bg = B + (long)bb * NN * DD;
  int i0 = (flat >> 5) * 128, j0 = (flat & 31) * 64;
  int tid = threadIdx.x, lane = tid & 63, w = tid >> 6;
  int wr = w >> 1, wc = w & 1;

  GEMM_MAIN();

#pragma unroll
  for (int mi = 0; mi < 4; mi++) {
#pragma unroll
    for (int nj = 0; nj < 2; nj++) {
#pragma unroll
      for (int r = 0; r < 4; r++) {
        int ig = i0 + wr * 64 + mi * 16 + (lane >> 4) * 4 + r;
        int jg = j0 + wc * 32 + nj * 16 + (lane & 15);
        out[((long)bb * DD + ig) * NN + jg] = acc[mi][nj][r] + bias[ig];
      }
    }
  }
}

// ---- flash attention, swapped-QK^T 32x32, K direct-to-register ------------
// Per wave: 32 q-rows. S^T = mfma(K, Q) -> lane holds P-row for q=lane&31.
// K frags loaded straight from global (L1/L2-resident, reused 16x per tile);
// V double-buffered in LDS via gld16. m==0 softmax (exp2 domain).
// P -> PV A-frags via cvt_pk_bf16 + permlane32_swap (T12).

__global__ __launch_bounds__(256) void attn_kernel(
    const unsigned short* __restrict__ Q, const unsigned short* __restrict__ Kg,
    const unsigned short* __restrict__ V, unsigned short* __restrict__ XA) {
  __shared__ unsigned short Vt[2][64 * 64];  // [hd][m] rows of 128B, swizzled
  int h = blockIdx.y, b = blockIdx.z;
  int tid = threadIdx.x, lane = tid & 63, w = tid >> 6;
  int l31 = lane & 31, hi = lane >> 5;
  int q0 = blockIdx.x * 128 + w * 32;
  long hb = (long)b * HH + h;
  const unsigned short* Qb = Q + hb * NN * HD;
  const unsigned short* Kb = Kg + hb * NN * HD;
  const unsigned short* Vb = V + hb * HD * NN;

  // Q B-frags: row = q0 + (lane&31), k chunks of 8 at hi*8 within each 16
  bf16x8 qf[4];
#pragma unroll
  for (int ks = 0; ks < 4; ks++)
    qf[ks] = *(const bf16x8*)(Qb + (long)(q0 + l31) * HD + ks * 16 + hi * 8);

  f32x16 oA[2];
#pragma unroll
  for (int hf = 0; hf < 2; hf++)
#pragma unroll
    for (int r = 0; r < 16; r++) oA[hf][r] = 0.f;
  float lsum = 0.f;

  auto stageV = [&](int vbuf, int t) {
    int m0 = t * 64;
#pragma unroll
    for (int c = 0; c < 2; c++) {
      int row = w * 16 + c * 8 + (lane >> 3);
      int so = ((lane & 7) * 16) ^ ((row & 7) << 4);
      gld16((const char*)Vb + ((long)row * NN + m0) * 2 + so,
            (char*)&Vt[vbuf][0] + (w * 16 + c * 8) * 128);
    }
  };
  auto loadK = [&](bf16x8 (&kf)[8], int t) {
    int m0 = t * 64;
#pragma unroll
    for (int kh = 0; kh < 2; kh++)
#pragma unroll
      for (int ks = 0; ks < 4; ks++)
        kf[kh * 4 + ks] =
            *(const bf16x8*)(Kb + (long)(m0 + kh * 32 + l31) * HD + ks * 16 + hi * 8);
  };
  auto body = [&](const bf16x8 (&kf)[8], int vbuf) {
#pragma unroll
    for (int kh = 0; kh < 2; kh++) {
      f32x16 s;
#pragma unroll
      for (int r = 0; r < 16; r++) s[r] = 0.f;
      __builtin_amdgcn_s_setprio(1);
#pragma unroll
      for (int ks = 0; ks < 4; ks++)
        s = __builtin_amdgcn_mfma_f32_32x32x16_bf16(kf[kh * 4 + ks], qf[ks], s, 0, 0, 0);
      __builtin_amdgcn_s_setprio(0);
      // P = exp2(S); accumulate l
      float p[16];
#pragma unroll
      for (int r = 0; r < 16; r++) {
        p[r] = __builtin_amdgcn_exp2f(s[r]);
        lsum += p[r];
      }
      // pack to bf16 pairs, then permlane32_swap to A-frag word layout
      unsigned pk[8];
#pragma unroll
      for (int i = 0; i < 8; i++)
        asm("v_cvt_pk_bf16_f32 %0, %1, %2"
            : "=v"(pk[i]) : "v"(p[2 * i]), "v"(p[2 * i + 1]));
      asm volatile("v_permlane32_swap_b32 %0, %1" : "+v"(pk[0]), "+v"(pk[2]));
      asm volatile("v_permlane32_swap_b32 %0, %1" : "+v"(pk[1]), "+v"(pk[3]));
      asm volatile("v_permlane32_swap_b32 %0, %1" : "+v"(pk[4]), "+v"(pk[6]));
      asm volatile("v_permlane32_swap_b32 %0, %1" : "+v"(pk[5]), "+v"(pk[7]));
      // PV: O[q][hd] += P * V
#pragma unroll
      for (int sv = 0; sv < 2; sv++) {
        union { bf16x8 v; unsigned u[4]; } fr;
        fr.u[0] = pk[sv * 4 + 0]; fr.u[1] = pk[sv * 4 + 1];
        fr.u[2] = pk[sv * 4 + 2]; fr.u[3] = pk[sv * 4 + 3];
        __builtin_amdgcn_s_setprio(1);
#pragma unroll
        for (int hf = 0; hf < 2; hf++) {
          int vrow = hf * 32 + l31;
          int voff = ((2 * kh + sv) * 32 + hi * 16) ^ ((vrow & 7) << 4);
          bf16x8 vf = *(const bf16x8*)((const char*)&Vt[vbuf][0] + vrow * 128 + voff);
          oA[hf] = __builtin_amdgcn_mfma_f32_32x32x16_bf16(fr.v, vf, oA[hf], 0, 0, 0);
        }
        __builtin_amdgcn_s_setprio(0);
      }
    }
  };

  bf16x8 kfA[8], kfB[8];
  loadK(kfA, 0);
  stageV(0, 0);
  __syncthreads();

  for (int t = 0; t < NN / 64; t += 2) {
    // even sub-iter: tile t (kfA, Vt[0]); prefetch t+1
    stageV(1, t + 1);
    loadK(kfB, t + 1);
    body(kfA, 0);
    __syncthreads();
    // odd sub-iter: tile t+1 (kfB, Vt[1]); prefetch t+2
    if (t + 2 < NN / 64) {
      stageV(0, t + 2);
      loadK(kfA, t + 2);
    }
    body(kfB, 1);
    __syncthreads();
  }

  // finalize: l = own half + partner half; normalize + write
  float lt = lsum + __shfl_xor(lsum, 32);
#pragma unroll
  for (int r = 0; r < 16; r++) {
    int qrow = (r & 3) + 8 * (r >> 2) + 4 * hi;  // C/D row for this reg
    float linv = 1.0f / __shfl(lt, qrow);
    long nrow = (long)b * NN + q0 + qrow;
#pragma unroll
    for (int hf = 0; hf < 2; hf++) {
      float val = oA[hf][r] * linv;
      XA[nrow * DD + h * HD + hf * 32 + l31] = f2bf(val);
    }
  }
}

// ---- host launcher --------------------------------------------------------

extern "C" void kernel_launch(void* const* d_in, const int* in_sizes, int n_in,
                              void* d_out, int out_size, void* d_ws, size_t ws_size,
                              hipStream_t stream) {
  const float* q_in = (const float*)d_in[0];
  const float* k_in = (const float*)d_in[1];
  const float* v_in = (const float*)d_in[2];
  const float* Wq = (const float*)d_in[3];
  const float* bq = (const float*)d_in[4];
  const float* Wk = (const float*)d_in[5];
  const float* bk = (const float*)d_in[6];
  const float* Wv = (const float*)d_in[7];
  const float* bv = (const float*)d_in[8];
  const float* Wm = (const float*)d_in[9];
  const float* bm = (const float*)d_in[10];
  float* out = (float*)d_out;

  const long SX = (long)BB * NN * DD;
  const long SW = (long)DD * DD;
  unsigned short* Xqt = (unsigned short*)d_ws;
  unsigned short* Xkt = Xqt + SX;
  unsigned short* Xvt = Xkt + SX;
  unsigned short* Qh = Xvt + SX;
  unsigned short* Kh = Qh + SX;
  unsigned short* Vh = Kh + SX;
  unsigned short* Wqt = Vh + SX;
  unsigned short* Wkt = Wqt + SW;
  unsigned short* Wvt = Wkt + SW;
  unsigned short* Wmt = Wvt + SW;
  unsigned short* XAt = Xqt;  // Xqt dead after Q projection
  if (ws_size < (size_t)(6 * SX + 4 * SW) * 2) return;

  dim3 blk(256);
  tcast_x<<<dim3(NN / 64, DD / 64, 24), blk, 0, stream>>>(
      q_in, k_in, v_in, Xqt, Xkt, Xvt);
  tcast_w<<<dim3(DD / 32, DD / 32, 4), blk, 0, stream>>>(
      Wq, Wk, Wv, Wm, Wqt, Wkt, Wvt, Wmt);
  gemm_qkv<<<dim3(16, 4, 24), blk, 0, stream>>>(
      Xqt, Xkt, Xvt, Wqt, Wkt, Wvt, bq, bk, bv, Qh, Kh, Vh);
  attn_kernel<<<dim3(NN / 128, HH, BB), blk, 0, stream>>>(Qh, Kh, Vh, XAt);
  gemm_out<<<dim3(16, 4, 8), blk, 0, stream>>>(Wmt, XAt, bm, out);
}

// Round 5
// 203.080 us; speedup vs baseline: 1.0628x; 1.0628x over previous
//
#include <hip/hip_runtime.h>
#include <stdint.h>

// Problem constants
#define BB 8
#define DD 256
#define NN 2048
#define HH 4
#define HD 64
// 0.125 (1/sqrt(64)) * log2(e): puts scores in log2-domain so P = exp2(S)
#define SCALE_Q 0.18033688011112042f

typedef __attribute__((ext_vector_type(8))) short bf16x8;   // 8 bf16 = 4 VGPRs
typedef __attribute__((ext_vector_type(4))) float f32x4;
typedef __attribute__((ext_vector_type(16))) float f32x16;

// ---- helpers --------------------------------------------------------------

__device__ __forceinline__ void gld16(const void* g, void* l) {
  // async global->LDS, 16B per lane; LDS dest = wave-uniform base + lane*16
  __builtin_amdgcn_global_load_lds(
      (__attribute__((address_space(1))) void*)(void*)(uintptr_t)(g),
      (__attribute__((address_space(3))) void*)(l), 16, 0, 0);
}

__device__ __forceinline__ unsigned short f2bf(float f) {
  union { float f; unsigned u; } v; v.f = f;
  unsigned lsb = (v.u >> 16) & 1u;
  v.u += 0x7fffu + lsb;               // RNE
  return (unsigned short)(v.u >> 16);
}

// ---- X transpose+cast: fp32 [B][D][N] -> bf16 [B][N][D], 64x64 tiles ------

__global__ __launch_bounds__(256) void tcast_x(
    const float* __restrict__ q, const float* __restrict__ k,
    const float* __restrict__ v, unsigned short* __restrict__ oq,
    unsigned short* __restrict__ ok2, unsigned short* __restrict__ ov) {
  __shared__ float t[64][65];
  int z = blockIdx.z, src = z >> 3, b = z & 7;
  const float* ip = (src == 0 ? q : src == 1 ? k : v) + (long)b * DD * NN;
  unsigned short* op = (src == 0 ? oq : src == 1 ? ok2 : ov) + (long)b * NN * DD;
  int c0 = blockIdx.x * 64, r0 = blockIdx.y * 64;
  int tx = threadIdx.x & 63, ty = threadIdx.x >> 6;
#pragma unroll
  for (int rr = 0; rr < 16; rr++) {
    int r = rr * 4 + ty;
    t[r][tx] = ip[(long)(r0 + r) * NN + c0 + tx];
  }
  __syncthreads();
#pragma unroll
  for (int rr = 0; rr < 16; rr++) {
    int c = rr * 4 + ty;
    op[(long)(c0 + c) * DD + r0 + tx] = f2bf(t[tx][c]);
  }
}

// ---- W transpose+cast with head permutation -------------------------------
// z<3 (Wq/Wk/Wv): out[j'][d] = s*W[d][o], j' = h*64+hd where o = hd*4+h
// z=3 (Wm):       out[o2][k'] = W[p(k')][o2]  (k-dim permuted to match XA)

__global__ __launch_bounds__(256) void tcast_w(
    const float* __restrict__ Wq, const float* __restrict__ Wk,
    const float* __restrict__ Wv, const float* __restrict__ Wm,
    unsigned short* __restrict__ oWq, unsigned short* __restrict__ oWk,
    unsigned short* __restrict__ oWv, unsigned short* __restrict__ oWm) {
  __shared__ float t[32][33];
  int z = blockIdx.z;
  const float* ip = z == 0 ? Wq : z == 1 ? Wk : z == 2 ? Wv : Wm;
  unsigned short* op = z == 0 ? oWq : z == 1 ? oWk : z == 2 ? oWv : oWm;
  float s = z == 0 ? SCALE_Q : 1.f;
  int c0 = blockIdx.x * 32, r0 = blockIdx.y * 32;
  int tx = threadIdx.x & 31, ty = threadIdx.x >> 5;
#pragma unroll
  for (int rr = 0; rr < 4; rr++) {
    int r = rr * 8 + ty;
    t[r][tx] = ip[(long)(r0 + r) * DD + c0 + tx];
  }
  __syncthreads();
  if (z < 3) {
#pragma unroll
    for (int rr = 0; rr < 4; rr++) {
      int c = rr * 8 + ty;
      int o = c0 + c;
      int jp = ((o & 3) << 6) | (o >> 2);   // inv_p: o=hd*4+h -> j'=h*64+hd
      op[(long)jp * DD + r0 + tx] = f2bf(s * t[tx][c]);
    }
  } else {
#pragma unroll
    for (int rr = 0; rr < 4; rr++) {
      int c = rr * 8 + ty;
      int d = r0 + tx;
      int kp = ((d & 3) << 6) | (d >> 2);
      op[(long)(c0 + c) * DD + kp] = f2bf(t[tx][c]);
    }
  }
}

// ---- shared GEMM core: 128(i) x 64(j) tile, K=256, 2-phase pipelined ------
// C[i][j] = sum_k A[i][k]*B[j][k]; A,B row-major [*][256] bf16.
// 4 waves as 2x2, each wave 64x32. acc[4][2] of 16x16 frags.

#define GEMM_STAGE(kt, buf)                                                    \
  {                                                                            \
    int _kt = (kt);                                                            \
    _Pragma("unroll") for (int c = 0; c < 4; c++) {                            \
      int row = w * 32 + c * 8 + (lane >> 3);                                  \
      int so = ((lane & 7) * 16) ^ ((row & 7) << 4);                           \
      gld16((const char*)Ag + ((long)(i0 + row) * DD + _kt * 64) * 2 + so,     \
            (char*)&At[buf][0] + (w * 32 + c * 8) * 128);                      \
    }                                                                          \
    _Pragma("unroll") for (int c = 0; c < 2; c++) {                            \
      int row = w * 16 + c * 8 + (lane >> 3);                                  \
      int so = ((lane & 7) * 16) ^ ((row & 7) << 4);                           \
      gld16((const char*)Bg + ((long)(j0 + row) * DD + _kt * 64) * 2 + so,     \
            (char*)&Bt[buf][0] + (w * 16 + c * 8) * 128);                      \
    }                                                                          \
  }

#define GEMM_COMPUTE(buf)                                                      \
  _Pragma("unroll") for (int ks = 0; ks < 2; ks++) {                           \
    bf16x8 af[4], bfv[2];                                                      \
    _Pragma("unroll") for (int mi = 0; mi < 4; mi++) {                         \
      int row = wr * 64 + mi * 16 + (lane & 15);                               \
      int off = (ks * 64 + (lane >> 4) * 16) ^ ((row & 7) << 4);               \
      af[mi] = *(const bf16x8*)((const char*)&At[buf][0] + row * 128 + off);   \
    }                                                                          \
    _Pragma("unroll") for (int nj = 0; nj < 2; nj++) {                         \
      int row = wc * 32 + nj * 16 + (lane & 15);                               \
      int off = (ks * 64 + (lane >> 4) * 16) ^ ((row & 7) << 4);               \
      bfv[nj] = *(const bf16x8*)((const char*)&Bt[buf][0] + row * 128 + off);  \
    }                                                                          \
    _Pragma("unroll") for (int mi = 0; mi < 4; mi++)                           \
        _Pragma("unroll") for (int nj = 0; nj < 2; nj++)                       \
            acc[mi][nj] = __builtin_amdgcn_mfma_f32_16x16x32_bf16(             \
                af[mi], bfv[nj], acc[mi][nj], 0, 0, 0);                        \
  }

#define GEMM_MAIN()                                                            \
  f32x4 acc[4][2];                                                             \
  _Pragma("unroll") for (int a = 0; a < 4; a++)                                \
      _Pragma("unroll") for (int c = 0; c < 2; c++)                            \
          acc[a][c] = (f32x4){0.f, 0.f, 0.f, 0.f};                             \
  GEMM_STAGE(0, 0);                                                            \
  __syncthreads();                                                             \
  int buf = 0;                                                                 \
  for (int kt = 0; kt < 4; kt++) {                                             \
    if (kt < 3) GEMM_STAGE(kt + 1, buf ^ 1);                                   \
    GEMM_COMPUTE(buf);                                                         \
    __syncthreads();                                                           \
    buf ^= 1;                                                                  \
  }

// ---- fused QKV projection GEMM --------------------------------------------
// proj 0/1: C[n][j'=h*64+hd] -> Qh/Kh [b][h][n][hd]
// proj 2:   C[i'=h*64+hd][m] -> Vh [b][h][hd][m]

__global__ __launch_bounds__(256) void gemm_qkv(
    const unsigned short* __restrict__ Xq, const unsigned short* __restrict__ Xk,
    const unsigned short* __restrict__ Xv, const unsigned short* __restrict__ Wq,
    const unsigned short* __restrict__ Wk, const unsigned short* __restrict__ Wv,
    const float* __restrict__ bq, const float* __restrict__ bk,
    const float* __restrict__ bv, unsigned short* __restrict__ Qh,
    unsigned short* __restrict__ Kh, unsigned short* __restrict__ Vh) {
  __shared__ unsigned short At[2][128 * 64], Bt[2][64 * 64];
  int z = blockIdx.z, proj = z >> 3, bb = z & 7;
  int flat = blockIdx.y * 16 + blockIdx.x;  // 0..63
  const unsigned short *Ag, *Bg;
  const float* bias;
  float bsc = 1.f;
  int i0, j0;
  if (proj == 0) {
    Ag = Xq + (long)bb * NN * DD; Bg = Wq; bias = bq; bsc = SCALE_Q;
    i0 = (flat & 15) * 128; j0 = (flat >> 4) * 64;
  } else if (proj == 1) {
    Ag = Xk + (long)bb * NN * DD; Bg = Wk; bias = bk;
    i0 = (flat & 15) * 128; j0 = (flat >> 4) * 64;
  } else {
    Ag = Wv; Bg = Xv + (long)bb * NN * DD; bias = bv;
    i0 = (flat >> 5) * 128; j0 = (flat & 31) * 64;
  }
  int tid = threadIdx.x, lane = tid & 63, w = tid >> 6;
  int wr = w >> 1, wc = w & 1;

  GEMM_MAIN();

#pragma unroll
  for (int mi = 0; mi < 4; mi++) {
#pragma unroll
    for (int nj = 0; nj < 2; nj++) {
#pragma unroll
      for (int r = 0; r < 4; r++) {
        int ig = i0 + wr * 64 + mi * 16 + (lane >> 4) * 4 + r;
        int jg = j0 + wc * 32 + nj * 16 + (lane & 15);
        float v = acc[mi][nj][r];
        if (proj < 2) {
          int o = ((jg & 63) << 2) | (jg >> 6);
          v += bias[o] * bsc;
          int hh = jg >> 6, hd = jg & 63;
          unsigned short* dst = proj == 0 ? Qh : Kh;
          dst[(((long)bb * HH + hh) * NN + ig) * HD + hd] = f2bf(v);
        } else {
          int o = ((ig & 63) << 2) | (ig >> 6);
          v += bias[o];
          int hh = ig >> 6, hd = ig & 63;
          Vh[(((long)bb * HH + hh) * HD + hd) * NN + jg] = f2bf(v);
        }
      }
    }
  }
}

// ---- output projection: C[o2][n] = sum_k Wmt[o2][k]*XA[n][k] + bm ---------

__global__ __launch_bounds__(256) void gemm_out(
    const unsigned short* __restrict__ A, const unsigned short* __restrict__ B,
    const float* __restrict__ bias, float* __restrict__ out) {
  __shared__ unsigned short At[2][128 * 64], Bt[2][64 * 64];
  int bb = blockIdx.z;
  int flat = blockIdx.y * 16 + blockIdx.x;
  const unsigned short* Ag = A;
  const unsigned short* Bg = B + (long)bb * NN * DD;
  int i0 = (flat >> 5) * 128, j0 = (flat & 31) * 64;
  int tid = threadIdx.x, lane = tid & 63, w = tid >> 6;
  int wr = w >> 1, wc = w & 1;

  GEMM_MAIN();

#pragma unroll
  for (int mi = 0; mi < 4; mi++) {
#pragma unroll
    for (int nj = 0; nj < 2; nj++) {
#pragma unroll
      for (int r = 0; r < 4; r++) {
        int ig = i0 + wr * 64 + mi * 16 + (lane >> 4) * 4 + r;
        int jg = j0 + wc * 32 + nj * 16 + (lane & 15);
        out[((long)bb * DD + ig) * NN + jg] = acc[mi][nj][r] + bias[ig];
      }
    }
  }
}

// ---- flash attention, swapped-QK^T 32x32, 64 q-rows per wave --------------
// 4 waves/block, 256 q/block, grid 256 blocks (1/CU), XCD-swizzled.
// Each K/V LDS frag read feeds TWO MFMAs (q-sets g=0,1) -> LDS bytes/MFMA
// halved vs r3; per-CU LDS (~750cyc) now under MFMA floor (~1088cyc).
// m==0 softmax (exp2 domain); P->A-frags via cvt_pk + permlane32_swap.

__global__ __launch_bounds__(256) void attn_kernel(
    const unsigned short* __restrict__ Q, const unsigned short* __restrict__ Kg,
    const unsigned short* __restrict__ V, unsigned short* __restrict__ XA) {
  __shared__ unsigned short Kt[2][64 * 64];  // [m][hd] rows of 128B, swizzled
  __shared__ unsigned short Vt[2][64 * 64];  // [hd][m] rows of 128B, swizzled
  // T1 bijective XCD swizzle: 256 blocks, 8 XCDs -> chunks of 32; each XCD
  // then holds 4 (h,b) K/V streams (~4MB) L2-resident.
  int flat = blockIdx.x;
  int work = (flat & 7) * 32 + (flat >> 3);
  int qb = work & 7, h = (work >> 3) & 3, b = work >> 5;
  int tid = threadIdx.x, lane = tid & 63, w = tid >> 6;
  int l31 = lane & 31, hi = lane >> 5;
  int qw = qb * 256 + w * 64;  // this wave's 64 q-rows
  long hb = (long)b * HH + h;
  const unsigned short* Qb = Q + hb * NN * HD;
  const unsigned short* Kb = Kg + hb * NN * HD;
  const unsigned short* Vb = V + hb * HD * NN;

  // Q B-frags for both 32-row sets g: row = qw + g*32 + l31
  bf16x8 qf[2][4];
#pragma unroll
  for (int g = 0; g < 2; g++)
#pragma unroll
    for (int ks = 0; ks < 4; ks++)
      qf[g][ks] =
          *(const bf16x8*)(Qb + (long)(qw + g * 32 + l31) * HD + ks * 16 + hi * 8);

  f32x16 oA[2][2];
#pragma unroll
  for (int g = 0; g < 2; g++)
#pragma unroll
    for (int hf = 0; hf < 2; hf++)
#pragma unroll
      for (int r = 0; r < 16; r++) oA[g][hf][r] = 0.f;
  float lsum0 = 0.f, lsum1 = 0.f;

  auto stage = [&](int buf, int t) {
    int m0 = t * 64;
#pragma unroll
    for (int c = 0; c < 2; c++) {
      int row = w * 16 + c * 8 + (lane >> 3);
      int so = ((lane & 7) * 16) ^ ((row & 7) << 4);
      gld16((const char*)Kb + (long)(m0 + row) * 128 + so,
            (char*)&Kt[buf][0] + (w * 16 + c * 8) * 128);
      gld16((const char*)Vb + ((long)row * NN + m0) * 2 + so,
            (char*)&Vt[buf][0] + (w * 16 + c * 8) * 128);
    }
  };

  int cur = 0;
  stage(0, 0);
  __syncthreads();

  for (int t = 0; t < NN / 64; t++) {
    if (t + 1 < NN / 64) stage(cur ^ 1, t + 1);

#pragma unroll
    for (int kh = 0; kh < 2; kh++) {
      // K A-frags for this 32-k-row group (shared by both q-sets)
      bf16x8 kf[4];
#pragma unroll
      for (int ks = 0; ks < 4; ks++) {
        int row = kh * 32 + l31;
        int off = (ks * 32 + hi * 16) ^ ((row & 7) << 4);
        kf[ks] = *(const bf16x8*)((const char*)&Kt[cur][0] + row * 128 + off);
      }
      f32x16 s0, s1;
#pragma unroll
      for (int r = 0; r < 16; r++) { s0[r] = 0.f; s1[r] = 0.f; }
      __builtin_amdgcn_s_setprio(1);
#pragma unroll
      for (int ks = 0; ks < 4; ks++) {
        s0 = __builtin_amdgcn_mfma_f32_32x32x16_bf16(kf[ks], qf[0][ks], s0, 0, 0, 0);
        s1 = __builtin_amdgcn_mfma_f32_32x32x16_bf16(kf[ks], qf[1][ks], s1, 0, 0, 0);
      }
      __builtin_amdgcn_s_setprio(0);
      // P = exp2(S) in place; accumulate l; pack + permlane to A-frag words
      unsigned pk0[8], pk1[8];
#pragma unroll
      for (int r = 0; r < 16; r++) {
        s0[r] = __builtin_amdgcn_exp2f(s0[r]);
        lsum0 += s0[r];
      }
#pragma unroll
      for (int i = 0; i < 8; i++)
        asm("v_cvt_pk_bf16_f32 %0, %1, %2"
            : "=v"(pk0[i]) : "v"(s0[2 * i]), "v"(s0[2 * i + 1]));
#pragma unroll
      for (int r = 0; r < 16; r++) {
        s1[r] = __builtin_amdgcn_exp2f(s1[r]);
        lsum1 += s1[r];
      }
#pragma unroll
      for (int i = 0; i < 8; i++)
        asm("v_cvt_pk_bf16_f32 %0, %1, %2"
            : "=v"(pk1[i]) : "v"(s1[2 * i]), "v"(s1[2 * i + 1]));
      asm volatile("v_permlane32_swap_b32 %0, %1" : "+v"(pk0[0]), "+v"(pk0[2]));
      asm volatile("v_permlane32_swap_b32 %0, %1" : "+v"(pk0[1]), "+v"(pk0[3]));
      asm volatile("v_permlane32_swap_b32 %0, %1" : "+v"(pk0[4]), "+v"(pk0[6]));
      asm volatile("v_permlane32_swap_b32 %0, %1" : "+v"(pk0[5]), "+v"(pk0[7]));
      asm volatile("v_permlane32_swap_b32 %0, %1" : "+v"(pk1[0]), "+v"(pk1[2]));
      asm volatile("v_permlane32_swap_b32 %0, %1" : "+v"(pk1[1]), "+v"(pk1[3]));
      asm volatile("v_permlane32_swap_b32 %0, %1" : "+v"(pk1[4]), "+v"(pk1[6]));
      asm volatile("v_permlane32_swap_b32 %0, %1" : "+v"(pk1[5]), "+v"(pk1[7]));
      // PV: k-steps 2kh+sv; each vf read feeds both q-sets
#pragma unroll
      for (int sv = 0; sv < 2; sv++) {
        union { bf16x8 v; unsigned u[4]; } fr0, fr1;
#pragma unroll
        for (int u = 0; u < 4; u++) {
          fr0.u[u] = pk0[sv * 4 + u];
          fr1.u[u] = pk1[sv * 4 + u];
        }
        __builtin_amdgcn_s_setprio(1);
#pragma unroll
        for (int hf = 0; hf < 2; hf++) {
          int vrow = hf * 32 + l31;
          int voff = ((2 * kh + sv) * 32 + hi * 16) ^ ((vrow & 7) << 4);
          bf16x8 vf = *(const bf16x8*)((const char*)&Vt[cur][0] + vrow * 128 + voff);
          oA[0][hf] = __builtin_amdgcn_mfma_f32_32x32x16_bf16(fr0.v, vf, oA[0][hf], 0, 0, 0);
          oA[1][hf] = __builtin_amdgcn_mfma_f32_32x32x16_bf16(fr1.v, vf, oA[1][hf], 0, 0, 0);
        }
        __builtin_amdgcn_s_setprio(0);
      }
    }
    __syncthreads();
    cur ^= 1;
  }

  // finalize per q-set: l = own half + partner half; normalize + write
#pragma unroll
  for (int g = 0; g < 2; g++) {
    float ls = g == 0 ? lsum0 : lsum1;
    float lt = ls + __shfl_xor(ls, 32);
#pragma unroll
    for (int r = 0; r < 16; r++) {
      int qrow = (r & 3) + 8 * (r >> 2) + 4 * hi;  // C/D row for this reg
      float linv = 1.0f / __shfl(lt, qrow);
      long nrow = (long)b * NN + qw + g * 32 + qrow;
#pragma unroll
      for (int hf = 0; hf < 2; hf++) {
        float val = oA[g][hf][r] * linv;
        XA[nrow * DD + h * HD + hf * 32 + l31] = f2bf(val);
      }
    }
  }
}

// ---- host launcher --------------------------------------------------------

extern "C" void kernel_launch(void* const* d_in, const int* in_sizes, int n_in,
                              void* d_out, int out_size, void* d_ws, size_t ws_size,
                              hipStream_t stream) {
  const float* q_in = (const float*)d_in[0];
  const float* k_in = (const float*)d_in[1];
  const float* v_in = (const float*)d_in[2];
  const float* Wq = (const float*)d_in[3];
  const float* bq = (const float*)d_in[4];
  const float* Wk = (const float*)d_in[5];
  const float* bk = (const float*)d_in[6];
  const float* Wv = (const float*)d_in[7];
  const float* bv = (const float*)d_in[8];
  const float* Wm = (const float*)d_in[9];
  const float* bm = (const float*)d_in[10];
  float* out = (float*)d_out;

  const long SX = (long)BB * NN * DD;
  const long SW = (long)DD * DD;
  unsigned short* Xqt = (unsigned short*)d_ws;
  unsigned short* Xkt = Xqt + SX;
  unsigned short* Xvt = Xkt + SX;
  unsigned short* Qh = Xvt + SX;
  unsigned short* Kh = Qh + SX;
  unsigned short* Vh = Kh + SX;
  unsigned short* Wqt = Vh + SX;
  unsigned short* Wkt = Wqt + SW;
  unsigned short* Wvt = Wkt + SW;
  unsigned short* Wmt = Wvt + SW;
  unsigned short* XAt = Xqt;  // Xqt dead after Q projection
  if (ws_size < (size_t)(6 * SX + 4 * SW) * 2) return;

  dim3 blk(256);
  tcast_x<<<dim3(NN / 64, DD / 64, 24), blk, 0, stream>>>(
      q_in, k_in, v_in, Xqt, Xkt, Xvt);
  tcast_w<<<dim3(DD / 32, DD / 32, 4), blk, 0, stream>>>(
      Wq, Wk, Wv, Wm, Wqt, Wkt, Wvt, Wmt);
  gemm_qkv<<<dim3(16, 4, 24), blk, 0, stream>>>(
      Xqt, Xkt, Xvt, Wqt, Wkt, Wvt, bq, bk, bv, Qh, Kh, Vh);
  attn_kernel<<<dim3(256), blk, 0, stream>>>(Qh, Kh, Vh, XAt);
  gemm_out<<<dim3(16, 4, 8), blk, 0, stream>>>(Wmt, XAt, bm, out);
}

// Round 6
// 191.980 us; speedup vs baseline: 1.1242x; 1.0578x over previous
//
#include <hip/hip_runtime.h>
#include <stdint.h>

// Problem constants
#define BB 8
#define DD 256
#define NN 2048
#define HH 4
#define HD 64
// 0.125 (1/sqrt(64)) * log2(e): puts scores in log2-domain so P = exp2(S)
#define SCALE_Q 0.18033688011112042f

typedef __attribute__((ext_vector_type(8))) short bf16x8;   // 8 bf16 = 4 VGPRs
typedef __attribute__((ext_vector_type(4))) float f32x4;
typedef __attribute__((ext_vector_type(16))) float f32x16;
typedef __attribute__((ext_vector_type(4))) unsigned short u16x4;

// ---- helpers --------------------------------------------------------------

__device__ __forceinline__ void gld16(const void* g, void* l) {
  // async global->LDS, 16B per lane; LDS dest = wave-uniform base + lane*16
  __builtin_amdgcn_global_load_lds(
      (__attribute__((address_space(1))) void*)(void*)(uintptr_t)(g),
      (__attribute__((address_space(3))) void*)(l), 16, 0, 0);
}

__device__ __forceinline__ unsigned short f2bf(float f) {
  union { float f; unsigned u; } v; v.f = f;
  unsigned lsb = (v.u >> 16) & 1u;
  v.u += 0x7fffu + lsb;               // RNE
  return (unsigned short)(v.u >> 16);
}

// ---- X transpose+cast: fp32 [B][D][N] -> bf16 [B][N][D], 64x64, vectorized
// float4 loads (16B/lane), LDS fp32 staging, ushort4 stores (8B/lane).

__global__ __launch_bounds__(256) void tcast_x(
    const float* __restrict__ q, const float* __restrict__ k,
    const float* __restrict__ v, unsigned short* __restrict__ oq,
    unsigned short* __restrict__ ok2, unsigned short* __restrict__ ov) {
  __shared__ float t[64][65];
  int z = blockIdx.z, src = z >> 3, b = z & 7;
  const float* ip = (src == 0 ? q : src == 1 ? k : v) + (long)b * DD * NN;
  unsigned short* op = (src == 0 ? oq : src == 1 ? ok2 : ov) + (long)b * NN * DD;
  int c0 = blockIdx.x * 64, r0 = blockIdx.y * 64;  // c0: n, r0: d
  int id = threadIdx.x;
  int hi4 = id >> 4, lo4 = id & 15;
#pragma unroll
  for (int r = 0; r < 4; r++) {
    int d = r * 16 + hi4;
    float4 vv = *(const float4*)(ip + (long)(r0 + d) * NN + c0 + lo4 * 4);
    t[d][lo4 * 4 + 0] = vv.x;
    t[d][lo4 * 4 + 1] = vv.y;
    t[d][lo4 * 4 + 2] = vv.z;
    t[d][lo4 * 4 + 3] = vv.w;
  }
  __syncthreads();
#pragma unroll
  for (int rr = 0; rr < 4; rr++) {
    int n = rr * 16 + hi4;
    u16x4 o4;
#pragma unroll
    for (int j = 0; j < 4; j++) o4[j] = f2bf(t[lo4 * 4 + j][n]);
    *(u16x4*)(op + (long)(c0 + n) * DD + r0 + lo4 * 4) = o4;
  }
}

// ---- W transpose+cast with head permutation -------------------------------
// z<3 (Wq/Wk/Wv): out[j'][d] = s*W[d][o], j' = h*64+hd where o = hd*4+h
// z=3 (Wm):       out[o2][k'] = W[p(k')][o2]  (k-dim permuted to match XA)

__global__ __launch_bounds__(256) void tcast_w(
    const float* __restrict__ Wq, const float* __restrict__ Wk,
    const float* __restrict__ Wv, const float* __restrict__ Wm,
    unsigned short* __restrict__ oWq, unsigned short* __restrict__ oWk,
    unsigned short* __restrict__ oWv, unsigned short* __restrict__ oWm) {
  __shared__ float t[32][33];
  int z = blockIdx.z;
  const float* ip = z == 0 ? Wq : z == 1 ? Wk : z == 2 ? Wv : Wm;
  unsigned short* op = z == 0 ? oWq : z == 1 ? oWk : z == 2 ? oWv : oWm;
  float s = z == 0 ? SCALE_Q : 1.f;
  int c0 = blockIdx.x * 32, r0 = blockIdx.y * 32;
  int tx = threadIdx.x & 31, ty = threadIdx.x >> 5;
#pragma unroll
  for (int rr = 0; rr < 4; rr++) {
    int r = rr * 8 + ty;
    t[r][tx] = ip[(long)(r0 + r) * DD + c0 + tx];
  }
  __syncthreads();
  if (z < 3) {
#pragma unroll
    for (int rr = 0; rr < 4; rr++) {
      int c = rr * 8 + ty;
      int o = c0 + c;
      int jp = ((o & 3) << 6) | (o >> 2);   // inv_p: o=hd*4+h -> j'=h*64+hd
      op[(long)jp * DD + r0 + tx] = f2bf(s * t[tx][c]);
    }
  } else {
#pragma unroll
    for (int rr = 0; rr < 4; rr++) {
      int c = rr * 8 + ty;
      int d = r0 + tx;
      int kp = ((d & 3) << 6) | (d >> 2);
      op[(long)(c0 + c) * DD + kp] = f2bf(t[tx][c]);
    }
  }
}

// ---- shared GEMM core: 128(i) x 64(j) tile, K=256, 2-phase pipelined ------

#define GEMM_STAGE(kt, buf)                                                    \
  {                                                                            \
    int _kt = (kt);                                                            \
    _Pragma("unroll") for (int c = 0; c < 4; c++) {                            \
      int row = w * 32 + c * 8 + (lane >> 3);                                  \
      int so = ((lane & 7) * 16) ^ ((row & 7) << 4);                           \
      gld16((const char*)Ag + ((long)(i0 + row) * DD + _kt * 64) * 2 + so,     \
            (char*)&At[buf][0] + (w * 32 + c * 8) * 128);                      \
    }                                                                          \
    _Pragma("unroll") for (int c = 0; c < 2; c++) {                            \
      int row = w * 16 + c * 8 + (lane >> 3);                                  \
      int so = ((lane & 7) * 16) ^ ((row & 7) << 4);                           \
      gld16((const char*)Bg + ((long)(j0 + row) * DD + _kt * 64) * 2 + so,     \
            (char*)&Bt[buf][0] + (w * 16 + c * 8) * 128);                      \
    }                                                                          \
  }

#define GEMM_COMPUTE(buf)                                                      \
  _Pragma("unroll") for (int ks = 0; ks < 2; ks++) {                           \
    bf16x8 af[4], bfv[2];                                                      \
    _Pragma("unroll") for (int mi = 0; mi < 4; mi++) {                         \
      int row = wr * 64 + mi * 16 + (lane & 15);                               \
      int off = (ks * 64 + (lane >> 4) * 16) ^ ((row & 7) << 4);               \
      af[mi] = *(const bf16x8*)((const char*)&At[buf][0] + row * 128 + off);   \
    }                                                                          \
    _Pragma("unroll") for (int nj = 0; nj < 2; nj++) {                         \
      int row = wc * 32 + nj * 16 + (lane & 15);                               \
      int off = (ks * 64 + (lane >> 4) * 16) ^ ((row & 7) << 4);               \
      bfv[nj] = *(const bf16x8*)((const char*)&Bt[buf][0] + row * 128 + off);  \
    }                                                                          \
    _Pragma("unroll") for (int mi = 0; mi < 4; mi++)                           \
        _Pragma("unroll") for (int nj = 0; nj < 2; nj++)                       \
            acc[mi][nj] = __builtin_amdgcn_mfma_f32_16x16x32_bf16(             \
                af[mi], bfv[nj], acc[mi][nj], 0, 0, 0);                        \
  }

#define GEMM_MAIN()                                                            \
  f32x4 acc[4][2];                                                             \
  _Pragma("unroll") for (int a = 0; a < 4; a++)                                \
      _Pragma("unroll") for (int c = 0; c < 2; c++)                            \
          acc[a][c] = (f32x4){0.f, 0.f, 0.f, 0.f};                             \
  GEMM_STAGE(0, 0);                                                            \
  __syncthreads();                                                             \
  int buf = 0;                                                                 \
  for (int kt = 0; kt < 4; kt++) {                                             \
    if (kt < 3) GEMM_STAGE(kt + 1, buf ^ 1);                                   \
    GEMM_COMPUTE(buf);                                                         \
    __syncthreads();                                                           \
    buf ^= 1;                                                                  \
  }

// ---- fused QKV projection GEMM --------------------------------------------
// proj 0/1: C[n][j'=h*64+hd] -> Qh/Kh [b][h][n][hd]
// proj 2:   C[i'=h*64+hd][m] -> Vh [b][h][hd][m]

__global__ __launch_bounds__(256) void gemm_qkv(
    const unsigned short* __restrict__ Xq, const unsigned short* __restrict__ Xk,
    const unsigned short* __restrict__ Xv, const unsigned short* __restrict__ Wq,
    const unsigned short* __restrict__ Wk, const unsigned short* __restrict__ Wv,
    const float* __restrict__ bq, const float* __restrict__ bk,
    const float* __restrict__ bv, unsigned short* __restrict__ Qh,
    unsigned short* __restrict__ Kh, unsigned short* __restrict__ Vh) {
  __shared__ unsigned short At[2][128 * 64], Bt[2][64 * 64];
  int z = blockIdx.z, proj = z >> 3, bb = z & 7;
  int flat = blockIdx.y * 16 + blockIdx.x;  // 0..63
  const unsigned short *Ag, *Bg;
  const float* bias;
  float bsc = 1.f;
  int i0, j0;
  if (proj == 0) {
    Ag = Xq + (long)bb * NN * DD; Bg = Wq; bias = bq; bsc = SCALE_Q;
    i0 = (flat & 15) * 128; j0 = (flat >> 4) * 64;
  } else if (proj == 1) {
    Ag = Xk + (long)bb * NN * DD; Bg = Wk; bias = bk;
    i0 = (flat & 15) * 128; j0 = (flat >> 4) * 64;
  } else {
    Ag = Wv; Bg = Xv + (long)bb * NN * DD; bias = bv;
    i0 = (flat >> 5) * 128; j0 = (flat & 31) * 64;
  }
  int tid = threadIdx.x, lane = tid & 63, w = tid >> 6;
  int wr = w >> 1, wc = w & 1;

  GEMM_MAIN();

#pragma unroll
  for (int mi = 0; mi < 4; mi++) {
#pragma unroll
    for (int nj = 0; nj < 2; nj++) {
#pragma unroll
      for (int r = 0; r < 4; r++) {
        int ig = i0 + wr * 64 + mi * 16 + (lane >> 4) * 4 + r;
        int jg = j0 + wc * 32 + nj * 16 + (lane & 15);
        float v = acc[mi][nj][r];
        if (proj < 2) {
          int o = ((jg & 63) << 2) | (jg >> 6);
          v += bias[o] * bsc;
          int hh = jg >> 6, hd = jg & 63;
          unsigned short* dst = proj == 0 ? Qh : Kh;
          dst[(((long)bb * HH + hh) * NN + ig) * HD + hd] = f2bf(v);
        } else {
          int o = ((ig & 63) << 2) | (ig >> 6);
          v += bias[o];
          int hh = ig >> 6, hd = ig & 63;
          Vh[(((long)bb * HH + hh) * HD + hd) * NN + jg] = f2bf(v);
        }
      }
    }
  }
}

// ---- output projection: C[o2][n] = sum_k Wmt[o2][k]*XA[n][k] + bm ---------

__global__ __launch_bounds__(256) void gemm_out(
    const unsigned short* __restrict__ A, const unsigned short* __restrict__ B,
    const float* __restrict__ bias, float* __restrict__ out) {
  __shared__ unsigned short At[2][128 * 64], Bt[2][64 * 64];
  int bb = blockIdx.z;
  int flat = blockIdx.y * 16 + blockIdx.x;
  const unsigned short* Ag = A;
  const unsigned short* Bg = B + (long)bb * NN * DD;
  int i0 = (flat >> 5) * 128, j0 = (flat & 31) * 64;
  int tid = threadIdx.x, lane = tid & 63, w = tid >> 6;
  int wr = w >> 1, wc = w & 1;

  GEMM_MAIN();

#pragma unroll
  for (int mi = 0; mi < 4; mi++) {
#pragma unroll
    for (int nj = 0; nj < 2; nj++) {
#pragma unroll
      for (int r = 0; r < 4; r++) {
        int ig = i0 + wr * 64 + mi * 16 + (lane >> 4) * 4 + r;
        int jg = j0 + wc * 32 + nj * 16 + (lane & 15);
        out[((long)bb * DD + ig) * NN + jg] = acc[mi][nj][r] + bias[ig];
      }
    }
  }
}

// ---- flash attention, swapped-QK^T 32x32 (r3 structure: 32q/wave, 2/SIMD) -
// + XCD-bijective swizzle (512=8x64): each XCD holds 4 (h,b) K/V streams
// (~4MB, L2-resident) and all 16 q-blocks of those streams.
// m==0 softmax (exp2 domain); P->A-frags via cvt_pk + permlane32_swap.

__global__ __launch_bounds__(256) void attn_kernel(
    const unsigned short* __restrict__ Q, const unsigned short* __restrict__ Kg,
    const unsigned short* __restrict__ V, unsigned short* __restrict__ XA) {
  __shared__ unsigned short Kt[2][64 * 64];  // [m][hd] rows of 128B, swizzled
  __shared__ unsigned short Vt[2][64 * 64];  // [hd][m] rows of 128B, swizzled
  int flat = blockIdx.x;
  int work = (flat & 7) * 64 + (flat >> 3);  // bijective XCD chunking
  int qb = work & 15, hbid = work >> 4;
  int h = hbid & 3, b = hbid >> 2;
  int tid = threadIdx.x, lane = tid & 63, w = tid >> 6;
  int l31 = lane & 31, hi = lane >> 5;
  int q0 = qb * 128 + w * 32;
  long hb = (long)b * HH + h;
  const unsigned short* Qb = Q + hb * NN * HD;
  const unsigned short* Kb = Kg + hb * NN * HD;
  const unsigned short* Vb = V + hb * HD * NN;

  const f32x16 FZ = {0.f, 0.f, 0.f, 0.f, 0.f, 0.f, 0.f, 0.f,
                     0.f, 0.f, 0.f, 0.f, 0.f, 0.f, 0.f, 0.f};

  // Q B-frags: row = q0 + (lane&31), k chunks of 8 at hi*8 within each 16
  bf16x8 qf[4];
#pragma unroll
  for (int ks = 0; ks < 4; ks++)
    qf[ks] = *(const bf16x8*)(Qb + (long)(q0 + l31) * HD + ks * 16 + hi * 8);

  f32x16 oA[2];
#pragma unroll
  for (int hf = 0; hf < 2; hf++)
#pragma unroll
    for (int r = 0; r < 16; r++) oA[hf][r] = 0.f;
  float lsum = 0.f;

  auto stage = [&](int buf, int t) {
    int m0 = t * 64;
#pragma unroll
    for (int c = 0; c < 2; c++) {
      int row = w * 16 + c * 8 + (lane >> 3);
      int so = ((lane & 7) * 16) ^ ((row & 7) << 4);
      gld16((const char*)Kb + (long)(m0 + row) * 128 + so,
            (char*)&Kt[buf][0] + (w * 16 + c * 8) * 128);
      gld16((const char*)Vb + ((long)row * NN + m0) * 2 + so,
            (char*)&Vt[buf][0] + (w * 16 + c * 8) * 128);
    }
  };

  int cur = 0;
  stage(0, 0);
  __syncthreads();

  for (int t = 0; t < NN / 64; t++) {
    if (t + 1 < NN / 64) stage(cur ^ 1, t + 1);

#pragma unroll
    for (int kh = 0; kh < 2; kh++) {
      // S^T[k=kh*32+..][q] : A = K rows (32 k-rows), B = Q
      f32x16 s;
#pragma unroll
      for (int ks = 0; ks < 4; ks++) {
        int row = kh * 32 + l31;
        int off = (ks * 32 + hi * 16) ^ ((row & 7) << 4);
        bf16x8 kf = *(const bf16x8*)((const char*)&Kt[cur][0] + row * 128 + off);
        s = __builtin_amdgcn_mfma_f32_32x32x16_bf16(kf, qf[ks],
                                                    ks == 0 ? FZ : s, 0, 0, 0);
      }
      // P = exp2(S); accumulate l
      float p[16];
#pragma unroll
      for (int r = 0; r < 16; r++) {
        p[r] = __builtin_amdgcn_exp2f(s[r]);
        lsum += p[r];
      }
      // pack to bf16 pairs, then permlane32_swap to A-frag word layout
      unsigned pk[8];
#pragma unroll
      for (int i = 0; i < 8; i++)
        asm("v_cvt_pk_bf16_f32 %0, %1, %2"
            : "=v"(pk[i]) : "v"(p[2 * i]), "v"(p[2 * i + 1]));
      asm volatile("v_permlane32_swap_b32 %0, %1" : "+v"(pk[0]), "+v"(pk[2]));
      asm volatile("v_permlane32_swap_b32 %0, %1" : "+v"(pk[1]), "+v"(pk[3]));
      asm volatile("v_permlane32_swap_b32 %0, %1" : "+v"(pk[4]), "+v"(pk[6]));
      asm volatile("v_permlane32_swap_b32 %0, %1" : "+v"(pk[5]), "+v"(pk[7]));
      // PV: O[q][hd] += P * V, k-steps s = 2kh, 2kh+1
#pragma unroll
      for (int sv = 0; sv < 2; sv++) {
        union { bf16x8 v; unsigned u[4]; } fr;
        fr.u[0] = pk[sv * 4 + 0]; fr.u[1] = pk[sv * 4 + 1];
        fr.u[2] = pk[sv * 4 + 2]; fr.u[3] = pk[sv * 4 + 3];
#pragma unroll
        for (int hf = 0; hf < 2; hf++) {
          int vrow = hf * 32 + l31;
          int voff = ((2 * kh + sv) * 32 + hi * 16) ^ ((vrow & 7) << 4);
          bf16x8 vf = *(const bf16x8*)((const char*)&Vt[cur][0] + vrow * 128 + voff);
          oA[hf] = __builtin_amdgcn_mfma_f32_32x32x16_bf16(fr.v, vf, oA[hf], 0, 0, 0);
        }
      }
    }
    __syncthreads();
    cur ^= 1;
  }

  // finalize: l = own half + partner half; normalize + write
  float lt = lsum + __shfl_xor(lsum, 32);
#pragma unroll
  for (int r = 0; r < 16; r++) {
    int qrow = (r & 3) + 8 * (r >> 2) + 4 * hi;  // C/D row for this reg
    float linv = 1.0f / __shfl(lt, qrow);
    long nrow = (long)b * NN + q0 + qrow;
#pragma unroll
    for (int hf = 0; hf < 2; hf++) {
      float val = oA[hf][r] * linv;
      XA[nrow * DD + h * HD + hf * 32 + l31] = f2bf(val);
    }
  }
}

// ---- host launcher --------------------------------------------------------

extern "C" void kernel_launch(void* const* d_in, const int* in_sizes, int n_in,
                              void* d_out, int out_size, void* d_ws, size_t ws_size,
                              hipStream_t stream) {
  const float* q_in = (const float*)d_in[0];
  const float* k_in = (const float*)d_in[1];
  const float* v_in = (const float*)d_in[2];
  const float* Wq = (const float*)d_in[3];
  const float* bq = (const float*)d_in[4];
  const float* Wk = (const float*)d_in[5];
  const float* bk = (const float*)d_in[6];
  const float* Wv = (const float*)d_in[7];
  const float* bv = (const float*)d_in[8];
  const float* Wm = (const float*)d_in[9];
  const float* bm = (const float*)d_in[10];
  float* out = (float*)d_out;

  const long SX = (long)BB * NN * DD;
  const long SW = (long)DD * DD;
  unsigned short* Xqt = (unsigned short*)d_ws;
  unsigned short* Xkt = Xqt + SX;
  unsigned short* Xvt = Xkt + SX;
  unsigned short* Qh = Xvt + SX;
  unsigned short* Kh = Qh + SX;
  unsigned short* Vh = Kh + SX;
  unsigned short* Wqt = Vh + SX;
  unsigned short* Wkt = Wqt + SW;
  unsigned short* Wvt = Wkt + SW;
  unsigned short* Wmt = Wvt + SW;
  unsigned short* XAt = Xqt;  // Xqt dead after Q projection
  if (ws_size < (size_t)(6 * SX + 4 * SW) * 2) return;

  dim3 blk(256);
  tcast_x<<<dim3(NN / 64, DD / 64, 24), blk, 0, stream>>>(
      q_in, k_in, v_in, Xqt, Xkt, Xvt);
  tcast_w<<<dim3(DD / 32, DD / 32, 4), blk, 0, stream>>>(
      Wq, Wk, Wv, Wm, Wqt, Wkt, Wvt, Wmt);
  gemm_qkv<<<dim3(16, 4, 24), blk, 0, stream>>>(
      Xqt, Xkt, Xvt, Wqt, Wkt, Wvt, bq, bk, bv, Qh, Kh, Vh);
  attn_kernel<<<dim3(512), blk, 0, stream>>>(Qh, Kh, Vh, XAt);
  gemm_out<<<dim3(16, 4, 8), blk, 0, stream>>>(Wmt, XAt, bm, out);
}

// Round 8
// 182.787 us; speedup vs baseline: 1.1808x; 1.0503x over previous
//
#include <hip/hip_runtime.h>
#include <stdint.h>

// Problem constants
#define BB 8
#define DD 256
#define NN 2048
#define HH 4
#define HD 64
// 0.125 (1/sqrt(64)) * log2(e): puts scores in log2-domain so P = exp2(S)
#define SCALE_Q 0.18033688011112042f

typedef __attribute__((ext_vector_type(8))) short bf16x8;   // 8 bf16 = 4 VGPRs
typedef __attribute__((ext_vector_type(4))) float f32x4;
typedef __attribute__((ext_vector_type(16))) float f32x16;
typedef __attribute__((ext_vector_type(4))) unsigned short u16x4;

// ---- helpers --------------------------------------------------------------

__device__ __forceinline__ void gld16(const void* g, void* l) {
  // async global->LDS, 16B per lane; LDS dest = wave-uniform base + lane*16
  __builtin_amdgcn_global_load_lds(
      (__attribute__((address_space(1))) void*)(void*)(uintptr_t)(g),
      (__attribute__((address_space(3))) void*)(l), 16, 0, 0);
}

__device__ __forceinline__ unsigned short f2bf(float f) {
  union { float f; unsigned u; } v; v.f = f;
  unsigned lsb = (v.u >> 16) & 1u;
  v.u += 0x7fffu + lsb;               // RNE
  return (unsigned short)(v.u >> 16);
}

// ---- X transpose+cast: fp32 [B][D][N] -> bf16 [B][N][D], 64x64, vectorized
// float4 loads (16B/lane), LDS fp32 staging, ushort4 stores (8B/lane).

__global__ __launch_bounds__(256) void tcast_x(
    const float* __restrict__ q, const float* __restrict__ k,
    const float* __restrict__ v, unsigned short* __restrict__ oq,
    unsigned short* __restrict__ ok2, unsigned short* __restrict__ ov) {
  __shared__ float t[64][65];
  int z = blockIdx.z, src = z >> 3, b = z & 7;
  const float* ip = (src == 0 ? q : src == 1 ? k : v) + (long)b * DD * NN;
  unsigned short* op = (src == 0 ? oq : src == 1 ? ok2 : ov) + (long)b * NN * DD;
  int c0 = blockIdx.x * 64, r0 = blockIdx.y * 64;  // c0: n, r0: d
  int id = threadIdx.x;
  int hi4 = id >> 4, lo4 = id & 15;
#pragma unroll
  for (int r = 0; r < 4; r++) {
    int d = r * 16 + hi4;
    float4 vv = *(const float4*)(ip + (long)(r0 + d) * NN + c0 + lo4 * 4);
    t[d][lo4 * 4 + 0] = vv.x;
    t[d][lo4 * 4 + 1] = vv.y;
    t[d][lo4 * 4 + 2] = vv.z;
    t[d][lo4 * 4 + 3] = vv.w;
  }
  __syncthreads();
#pragma unroll
  for (int rr = 0; rr < 4; rr++) {
    int n = rr * 16 + hi4;
    u16x4 o4;
#pragma unroll
    for (int j = 0; j < 4; j++) o4[j] = f2bf(t[lo4 * 4 + j][n]);
    *(u16x4*)(op + (long)(c0 + n) * DD + r0 + lo4 * 4) = o4;
  }
}

// ---- W transpose+cast with head permutation -------------------------------
// z<3 (Wq/Wk/Wv): out[j'][d] = s*W[d][o], j' = h*64+hd where o = hd*4+h
// z=3 (Wm):       out[o2][k'] = W[p(k')][o2]  (k-dim permuted to match XA)

__global__ __launch_bounds__(256) void tcast_w(
    const float* __restrict__ Wq, const float* __restrict__ Wk,
    const float* __restrict__ Wv, const float* __restrict__ Wm,
    unsigned short* __restrict__ oWq, unsigned short* __restrict__ oWk,
    unsigned short* __restrict__ oWv, unsigned short* __restrict__ oWm) {
  __shared__ float t[32][33];
  int z = blockIdx.z;
  const float* ip = z == 0 ? Wq : z == 1 ? Wk : z == 2 ? Wv : Wm;
  unsigned short* op = z == 0 ? oWq : z == 1 ? oWk : z == 2 ? oWv : oWm;
  float s = z == 0 ? SCALE_Q : 1.f;
  int c0 = blockIdx.x * 32, r0 = blockIdx.y * 32;
  int tx = threadIdx.x & 31, ty = threadIdx.x >> 5;
#pragma unroll
  for (int rr = 0; rr < 4; rr++) {
    int r = rr * 8 + ty;
    t[r][tx] = ip[(long)(r0 + r) * DD + c0 + tx];
  }
  __syncthreads();
  if (z < 3) {
#pragma unroll
    for (int rr = 0; rr < 4; rr++) {
      int c = rr * 8 + ty;
      int o = c0 + c;
      int jp = ((o & 3) << 6) | (o >> 2);   // inv_p: o=hd*4+h -> j'=h*64+hd
      op[(long)jp * DD + r0 + tx] = f2bf(s * t[tx][c]);
    }
  } else {
#pragma unroll
    for (int rr = 0; rr < 4; rr++) {
      int c = rr * 8 + ty;
      int d = r0 + tx;
      int kp = ((d & 3) << 6) | (d >> 2);
      op[(long)(c0 + c) * DD + kp] = f2bf(t[tx][c]);
    }
  }
}

// ---- shared GEMM core: 128(i) x 64(j) tile, K=256, 2-phase pipelined ------

#define GEMM_STAGE(kt, buf)                                                    \
  {                                                                            \
    int _kt = (kt);                                                            \
    _Pragma("unroll") for (int c = 0; c < 4; c++) {                            \
      int row = w * 32 + c * 8 + (lane >> 3);                                  \
      int so = ((lane & 7) * 16) ^ ((row & 7) << 4);                           \
      gld16((const char*)Ag + ((long)(i0 + row) * DD + _kt * 64) * 2 + so,     \
            (char*)&At[buf][0] + (w * 32 + c * 8) * 128);                      \
    }                                                                          \
    _Pragma("unroll") for (int c = 0; c < 2; c++) {                            \
      int row = w * 16 + c * 8 + (lane >> 3);                                  \
      int so = ((lane & 7) * 16) ^ ((row & 7) << 4);                           \
      gld16((const char*)Bg + ((long)(j0 + row) * DD + _kt * 64) * 2 + so,     \
            (char*)&Bt[buf][0] + (w * 16 + c * 8) * 128);                      \
    }                                                                          \
  }

#define GEMM_COMPUTE(buf)                                                      \
  _Pragma("unroll") for (int ks = 0; ks < 2; ks++) {                           \
    bf16x8 af[4], bfv[2];                                                      \
    _Pragma("unroll") for (int mi = 0; mi < 4; mi++) {                         \
      int row = wr * 64 + mi * 16 + (lane & 15);                               \
      int off = (ks * 64 + (lane >> 4) * 16) ^ ((row & 7) << 4);               \
      af[mi] = *(const bf16x8*)((const char*)&At[buf][0] + row * 128 + off);   \
    }                                                                          \
    _Pragma("unroll") for (int nj = 0; nj < 2; nj++) {                         \
      int row = wc * 32 + nj * 16 + (lane & 15);                               \
      int off = (ks * 64 + (lane >> 4) * 16) ^ ((row & 7) << 4);               \
      bfv[nj] = *(const bf16x8*)((const char*)&Bt[buf][0] + row * 128 + off);  \
    }                                                                          \
    _Pragma("unroll") for (int mi = 0; mi < 4; mi++)                           \
        _Pragma("unroll") for (int nj = 0; nj < 2; nj++)                       \
            acc[mi][nj] = __builtin_amdgcn_mfma_f32_16x16x32_bf16(             \
                af[mi], bfv[nj], acc[mi][nj], 0, 0, 0);                        \
  }

#define GEMM_MAIN()                                                            \
  f32x4 acc[4][2];                                                             \
  _Pragma("unroll") for (int a = 0; a < 4; a++)                                \
      _Pragma("unroll") for (int c = 0; c < 2; c++)                            \
          acc[a][c] = (f32x4){0.f, 0.f, 0.f, 0.f};                             \
  GEMM_STAGE(0, 0);                                                            \
  __syncthreads();                                                             \
  int buf = 0;                                                                 \
  for (int kt = 0; kt < 4; kt++) {                                             \
    if (kt < 3) GEMM_STAGE(kt + 1, buf ^ 1);                                   \
    GEMM_COMPUTE(buf);                                                         \
    __syncthreads();                                                           \
    buf ^= 1;                                                                  \
  }

// ---- fused QKV projection GEMM --------------------------------------------
// proj 0/1: C[n][j'=h*64+hd] -> Qh/Kh [b][h][n][hd]
// proj 2:   C[i'=h*64+hd][m] -> Vh [b][h][hd][m]

__global__ __launch_bounds__(256) void gemm_qkv(
    const unsigned short* __restrict__ Xq, const unsigned short* __restrict__ Xk,
    const unsigned short* __restrict__ Xv, const unsigned short* __restrict__ Wq,
    const unsigned short* __restrict__ Wk, const unsigned short* __restrict__ Wv,
    const float* __restrict__ bq, const float* __restrict__ bk,
    const float* __restrict__ bv, unsigned short* __restrict__ Qh,
    unsigned short* __restrict__ Kh, unsigned short* __restrict__ Vh) {
  __shared__ unsigned short At[2][128 * 64], Bt[2][64 * 64];
  int z = blockIdx.z, proj = z >> 3, bb = z & 7;
  int flat = blockIdx.y * 16 + blockIdx.x;  // 0..63
  const unsigned short *Ag, *Bg;
  const float* bias;
  float bsc = 1.f;
  int i0, j0;
  if (proj == 0) {
    Ag = Xq + (long)bb * NN * DD; Bg = Wq; bias = bq; bsc = SCALE_Q;
    i0 = (flat & 15) * 128; j0 = (flat >> 4) * 64;
  } else if (proj == 1) {
    Ag = Xk + (long)bb * NN * DD; Bg = Wk; bias = bk;
    i0 = (flat & 15) * 128; j0 = (flat >> 4) * 64;
  } else {
    Ag = Wv; Bg = Xv + (long)bb * NN * DD; bias = bv;
    i0 = (flat >> 5) * 128; j0 = (flat & 31) * 64;
  }
  int tid = threadIdx.x, lane = tid & 63, w = tid >> 6;
  int wr = w >> 1, wc = w & 1;

  GEMM_MAIN();

#pragma unroll
  for (int mi = 0; mi < 4; mi++) {
#pragma unroll
    for (int nj = 0; nj < 2; nj++) {
#pragma unroll
      for (int r = 0; r < 4; r++) {
        int ig = i0 + wr * 64 + mi * 16 + (lane >> 4) * 4 + r;
        int jg = j0 + wc * 32 + nj * 16 + (lane & 15);
        float v = acc[mi][nj][r];
        if (proj < 2) {
          int o = ((jg & 63) << 2) | (jg >> 6);
          v += bias[o] * bsc;
          int hh = jg >> 6, hd = jg & 63;
          unsigned short* dst = proj == 0 ? Qh : Kh;
          dst[(((long)bb * HH + hh) * NN + ig) * HD + hd] = f2bf(v);
        } else {
          int o = ((ig & 63) << 2) | (ig >> 6);
          v += bias[o];
          int hh = ig >> 6, hd = ig & 63;
          Vh[(((long)bb * HH + hh) * HD + hd) * NN + jg] = f2bf(v);
        }
      }
    }
  }
}

// ---- output projection: C[o2][n] = sum_k Wmt[o2][k]*XA[n][k] + bm ---------

__global__ __launch_bounds__(256) void gemm_out(
    const unsigned short* __restrict__ A, const unsigned short* __restrict__ B,
    const float* __restrict__ bias, float* __restrict__ out) {
  __shared__ unsigned short At[2][128 * 64], Bt[2][64 * 64];
  int bb = blockIdx.z;
  int flat = blockIdx.y * 16 + blockIdx.x;
  const unsigned short* Ag = A;
  const unsigned short* Bg = B + (long)bb * NN * DD;
  int i0 = (flat >> 5) * 128, j0 = (flat & 31) * 64;
  int tid = threadIdx.x, lane = tid & 63, w = tid >> 6;
  int wr = w >> 1, wc = w & 1;

  GEMM_MAIN();

#pragma unroll
  for (int mi = 0; mi < 4; mi++) {
#pragma unroll
    for (int nj = 0; nj < 2; nj++) {
#pragma unroll
      for (int r = 0; r < 4; r++) {
        int ig = i0 + wr * 64 + mi * 16 + (lane >> 4) * 4 + r;
        int jg = j0 + wc * 32 + nj * 16 + (lane & 15);
        out[((long)bb * DD + ig) * NN + jg] = acc[mi][nj][r] + bias[ig];
      }
    }
  }
}

// ---- flash attention, swapped-QK^T 32x32, intra-block KV-split x2 ---------
// 8 waves/block (512 thr): waves 0-3 = q-sets 0-3 over KV[0,1024),
// waves 4-7 = same q-sets over KV[1024,2048). Each half double-buffers its
// own K/V tiles (64KB LDS). 512 blocks -> 2 blocks/CU = 4 waves/SIMD (vs 2).
// m==0 softmax makes the merge trivial: O += O', l += l' (no rescale).
// P->A-frags via cvt_pk + permlane32_swap; XCD-bijective block swizzle.

__global__ __launch_bounds__(512, 4) void attn_kernel(
    const unsigned short* __restrict__ Q, const unsigned short* __restrict__ Kg,
    const unsigned short* __restrict__ V, unsigned short* __restrict__ XA) {
  __shared__ unsigned short Kt[2][2][64 * 64];  // [half][dbuf][m][hd] swizzled
  __shared__ unsigned short Vt[2][2][64 * 64];  // [half][dbuf][hd][m] swizzled
  int flat = blockIdx.x;
  int work = (flat & 7) * 64 + (flat >> 3);  // bijective XCD chunking
  int qb = work & 15, hbid = work >> 4;
  int h = hbid & 3, b = hbid >> 2;
  int tid = threadIdx.x, lane = tid & 63, w = tid >> 6;
  int qs = w & 3, half = w >> 2;
  int l31 = lane & 31, hi = lane >> 5;
  int q0 = qb * 128 + qs * 32;
  long hb = (long)b * HH + h;
  const unsigned short* Qb = Q + hb * NN * HD;
  const unsigned short* Kb = Kg + hb * NN * HD;
  const unsigned short* Vb = V + hb * HD * NN;

  const f32x16 FZ = {0.f, 0.f, 0.f, 0.f, 0.f, 0.f, 0.f, 0.f,
                     0.f, 0.f, 0.f, 0.f, 0.f, 0.f, 0.f, 0.f};

  // Q B-frags: row = q0 + (lane&31), k chunks of 8 at hi*8 within each 16
  bf16x8 qf[4];
#pragma unroll
  for (int ks = 0; ks < 4; ks++)
    qf[ks] = *(const bf16x8*)(Qb + (long)(q0 + l31) * HD + ks * 16 + hi * 8);

  f32x16 oA[2];
#pragma unroll
  for (int hf = 0; hf < 2; hf++)
#pragma unroll
    for (int r = 0; r < 16; r++) oA[hf][r] = 0.f;
  float lsum = 0.f;

  auto stage = [&](int buf, int t) {  // t = global tile index for this half
    int m0 = t * 64;
#pragma unroll
    for (int c = 0; c < 2; c++) {
      int row = qs * 16 + c * 8 + (lane >> 3);
      int so = ((lane & 7) * 16) ^ ((row & 7) << 4);
      gld16((const char*)Kb + (long)(m0 + row) * 128 + so,
            (char*)&Kt[half][buf][0] + (qs * 16 + c * 8) * 128);
      gld16((const char*)Vb + ((long)row * NN + m0) * 2 + so,
            (char*)&Vt[half][buf][0] + (qs * 16 + c * 8) * 128);
    }
  };

  const int HT = NN / 64 / 2;  // 16 tiles per half
  int cur = 0;
  stage(0, half * HT);
  __syncthreads();

  for (int tt = 0; tt < HT; tt++) {
    if (tt + 1 < HT) stage(cur ^ 1, half * HT + tt + 1);

#pragma unroll
    for (int kh = 0; kh < 2; kh++) {
      // S^T[k=kh*32+..][q] : A = K rows (32 k-rows), B = Q
      f32x16 s;
#pragma unroll
      for (int ks = 0; ks < 4; ks++) {
        int row = kh * 32 + l31;
        int off = (ks * 32 + hi * 16) ^ ((row & 7) << 4);
        bf16x8 kf = *(const bf16x8*)((const char*)&Kt[half][cur][0] + row * 128 + off);
        s = __builtin_amdgcn_mfma_f32_32x32x16_bf16(kf, qf[ks],
                                                    ks == 0 ? FZ : s, 0, 0, 0);
      }
      // P = exp2(S); accumulate l (tree to break the serial add chain)
      float p[16];
#pragma unroll
      for (int r = 0; r < 16; r++) p[r] = __builtin_amdgcn_exp2f(s[r]);
      float t0 = ((p[0] + p[1]) + (p[2] + p[3])) + ((p[4] + p[5]) + (p[6] + p[7]));
      float t1 = ((p[8] + p[9]) + (p[10] + p[11])) + ((p[12] + p[13]) + (p[14] + p[15]));
      lsum += t0 + t1;
      // pack to bf16 pairs, then permlane32_swap to A-frag word layout
      unsigned pk[8];
#pragma unroll
      for (int i = 0; i < 8; i++)
        asm("v_cvt_pk_bf16_f32 %0, %1, %2"
            : "=v"(pk[i]) : "v"(p[2 * i]), "v"(p[2 * i + 1]));
      asm volatile("v_permlane32_swap_b32 %0, %1" : "+v"(pk[0]), "+v"(pk[2]));
      asm volatile("v_permlane32_swap_b32 %0, %1" : "+v"(pk[1]), "+v"(pk[3]));
      asm volatile("v_permlane32_swap_b32 %0, %1" : "+v"(pk[4]), "+v"(pk[6]));
      asm volatile("v_permlane32_swap_b32 %0, %1" : "+v"(pk[5]), "+v"(pk[7]));
      // PV: O[q][hd] += P * V, k-steps s = 2kh, 2kh+1
#pragma unroll
      for (int sv = 0; sv < 2; sv++) {
        union { bf16x8 v; unsigned u[4]; } fr;
        fr.u[0] = pk[sv * 4 + 0]; fr.u[1] = pk[sv * 4 + 1];
        fr.u[2] = pk[sv * 4 + 2]; fr.u[3] = pk[sv * 4 + 3];
#pragma unroll
        for (int hf = 0; hf < 2; hf++) {
          int vrow = hf * 32 + l31;
          int voff = ((2 * kh + sv) * 32 + hi * 16) ^ ((vrow & 7) << 4);
          bf16x8 vf = *(const bf16x8*)((const char*)&Vt[half][cur][0] + vrow * 128 + voff);
          oA[hf] = __builtin_amdgcn_mfma_f32_32x32x16_bf16(fr.v, vf, oA[hf], 0, 0, 0);
        }
      }
    }
    __syncthreads();
    cur ^= 1;
  }

  // ---- merge halves via LDS overlay (K/V buffers are dead now) ----
  float* mrgO = (float*)&Kt[0][0][0];  // 8192 floats = 32KB
  float* mrgL = (float*)&Vt[0][0][0];  // 256 floats
  if (half == 1) {
#pragma unroll
    for (int hf = 0; hf < 2; hf++)
#pragma unroll
      for (int r = 0; r < 16; r++)
        mrgO[qs * 2048 + hf * 1024 + r * 64 + lane] = oA[hf][r];
    mrgL[qs * 64 + lane] = lsum;
  }
  __syncthreads();
  if (half == 0) {
#pragma unroll
    for (int hf = 0; hf < 2; hf++)
#pragma unroll
      for (int r = 0; r < 16; r++)
        oA[hf][r] += mrgO[qs * 2048 + hf * 1024 + r * 64 + lane];
    lsum += mrgL[qs * 64 + lane];
    // finalize: l = own half-lane + partner (hi) half; normalize + write
    float lt = lsum + __shfl_xor(lsum, 32);
#pragma unroll
    for (int r = 0; r < 16; r++) {
      int qrow = (r & 3) + 8 * (r >> 2) + 4 * hi;  // C/D row for this reg
      float linv = 1.0f / __shfl(lt, qrow);
      long nrow = (long)b * NN + q0 + qrow;
#pragma unroll
      for (int hf = 0; hf < 2; hf++) {
        float val = oA[hf][r] * linv;
        XA[nrow * DD + h * HD + hf * 32 + l31] = f2bf(val);
      }
    }
  }
}

// ---- host launcher --------------------------------------------------------

extern "C" void kernel_launch(void* const* d_in, const int* in_sizes, int n_in,
                              void* d_out, int out_size, void* d_ws, size_t ws_size,
                              hipStream_t stream) {
  const float* q_in = (const float*)d_in[0];
  const float* k_in = (const float*)d_in[1];
  const float* v_in = (const float*)d_in[2];
  const float* Wq = (const float*)d_in[3];
  const float* bq = (const float*)d_in[4];
  const float* Wk = (const float*)d_in[5];
  const float* bk = (const float*)d_in[6];
  const float* Wv = (const float*)d_in[7];
  const float* bv = (const float*)d_in[8];
  const float* Wm = (const float*)d_in[9];
  const float* bm = (const float*)d_in[10];
  float* out = (float*)d_out;

  const long SX = (long)BB * NN * DD;
  const long SW = (long)DD * DD;
  unsigned short* Xqt = (unsigned short*)d_ws;
  unsigned short* Xkt = Xqt + SX;
  unsigned short* Xvt = Xkt + SX;
  unsigned short* Qh = Xvt + SX;
  unsigned short* Kh = Qh + SX;
  unsigned short* Vh = Kh + SX;
  unsigned short* Wqt = Vh + SX;
  unsigned short* Wkt = Wqt + SW;
  unsigned short* Wvt = Wkt + SW;
  unsigned short* Wmt = Wvt + SW;
  unsigned short* XAt = Xqt;  // Xqt dead after Q projection
  if (ws_size < (size_t)(6 * SX + 4 * SW) * 2) return;

  dim3 blk(256);
  tcast_x<<<dim3(NN / 64, DD / 64, 24), blk, 0, stream>>>(
      q_in, k_in, v_in, Xqt, Xkt, Xvt);
  tcast_w<<<dim3(DD / 32, DD / 32, 4), blk, 0, stream>>>(
      Wq, Wk, Wv, Wm, Wqt, Wkt, Wvt, Wmt);
  gemm_qkv<<<dim3(16, 4, 24), blk, 0, stream>>>(
      Xqt, Xkt, Xvt, Wqt, Wkt, Wvt, bq, bk, bv, Qh, Kh, Vh);
  attn_kernel<<<dim3(512), dim3(512), 0, stream>>>(Qh, Kh, Vh, XAt);
  gemm_out<<<dim3(16, 4, 8), blk, 0, stream>>>(Wmt, XAt, bm, out);
}